// Round 3
// baseline (481.933 us; speedup 1.0000x reference)
//
#include <hip/hip_runtime.h>

typedef __bf16 bf16;
typedef __attribute__((ext_vector_type(4))) __bf16 bf16x4;
typedef __attribute__((ext_vector_type(8))) __bf16 bf16x8;
typedef __attribute__((ext_vector_type(4))) float f32x4;

#define DEVINL __device__ __forceinline__

typedef __attribute__((address_space(1))) void gvoid_t;
typedef __attribute__((address_space(3))) void lvoid_t;

DEVINL void async_ld16(const void* g, void* l) {
    __builtin_amdgcn_global_load_lds((gvoid_t*)g, (lvoid_t*)l, 16, 0, 0);
}

// C(M x N) = relu(A(M x K) @ Bt^T + bias); A,Bt bf16; bias f32.
// 128x128 tile, BK=64, 256 threads = 4 waves (2x2 of 64x64), 16x16x32 bf16 MFMA.
// MODE 0: A gathered from obj_bf/pred_bf via edges (K=1536, S|P|O), out -> Dbf (hid)
// MODE 1: split epilogue: bn<4 atomicAdd pooled[s]; bn in [4,8) store Df (out_p, f32);
//         bn>=8 atomicAdd pooled[o]
// MODE 2: plain -> Dbf (h2).  MODE 3: plain -> Df (out_obj, f32)
template<int MODE>
__global__ __launch_bounds__(256, 2) void gemm_k(
    const bf16* __restrict__ A, const bf16* __restrict__ Bt,
    const float* __restrict__ bias, bf16* __restrict__ Dbf,
    float* __restrict__ Df, const int* __restrict__ edges,
    const bf16* __restrict__ obj, const bf16* __restrict__ pred,
    float* __restrict__ pooledP, int K)
{
    const int tid = threadIdx.x;
    const int bm = blockIdx.x;
    const int bn = blockIdx.y;

    __shared__ __align__(16) bf16 ldsA[128 * 64];
    __shared__ __align__(16) bf16 ldsB[128 * 64];

    // staging: thread covers granule flat = tid + 256*i -> row flat>>3, slot tid&7
    const int g_slot = tid & 7;
    const int row0 = tid >> 3;

    unsigned offS[4], offP[4], offO[4], offA[4], offB[4];
#pragma unroll
    for (int i = 0; i < 4; i++) {
        int r = row0 + 32 * i;
        int gr = bm * 128 + r;
        if (MODE == 0) {
            int b = gr >> 9;  // T = 512
            int s = edges[gr * 3 + 0] & 255;
            int o = edges[gr * 3 + 2] & 255;
            offS[i] = (unsigned)(b * 256 + s) * 512u;
            offP[i] = (unsigned)gr * 512u;
            offO[i] = (unsigned)(b * 256 + o) * 512u;
        } else {
            offA[i] = (unsigned)gr * (unsigned)K;
        }
        offB[i] = (unsigned)(bn * 128 + r) * (unsigned)K;
    }

    f32x4 acc[4][4];
    const f32x4 zero4 = {0.f, 0.f, 0.f, 0.f};
#pragma unroll
    for (int i = 0; i < 4; i++)
#pragma unroll
        for (int j = 0; j < 4; j++) acc[i][j] = zero4;

    const int wave = tid >> 6;
    const int lane = tid & 63;
    const int wr = (wave >> 1) * 64;
    const int wc = (wave & 1) * 64;
    const int lq = lane >> 4;
    const int lr = lane & 15;

    const int KT = K >> 6;
    for (int kt = 0; kt < KT; ++kt) {
        __syncthreads();  // prior iter's LDS reads complete in all waves
        // stage A: LDS slot (r, g_slot) holds global granule g_slot^(r&7)
#pragma unroll
        for (int i = 0; i < 4; i++) {
            int r = row0 + 32 * i;
            int gsrc = g_slot ^ (r & 7);
            const bf16* gp;
            if (MODE == 0) {
                int region = kt >> 3;  // wave-uniform
                unsigned col = (unsigned)((kt & 7) * 64 + gsrc * 8);
                if (region == 0)      gp = obj + offS[i] + col;
                else if (region == 1) gp = pred + offP[i] + col;
                else                  gp = obj + offO[i] + col;
            } else {
                gp = A + offA[i] + (unsigned)(kt * 64 + gsrc * 8);
            }
            async_ld16(gp, ldsA + (tid + i * 256) * 8);
        }
#pragma unroll
        for (int i = 0; i < 4; i++) {
            int r = row0 + 32 * i;
            int gsrc = g_slot ^ (r & 7);
            async_ld16(Bt + offB[i] + (unsigned)(kt * 64 + gsrc * 8),
                       ldsB + (tid + i * 256) * 8);
        }
        __syncthreads();  // vmcnt(0) drain -> tiles ready

#pragma unroll
        for (int ks = 0; ks < 2; ++ks) {
            bf16x8 af[4], bfr[4];
#pragma unroll
            for (int mi = 0; mi < 4; ++mi) {
                int r = wr + mi * 16 + lr;
                int g = (ks * 4 + lq) ^ (r & 7);
                af[mi] = *(const bf16x8*)(ldsA + (r * 8 + g) * 8);
            }
#pragma unroll
            for (int ni = 0; ni < 4; ++ni) {
                int r = wc + ni * 16 + lr;
                int g = (ks * 4 + lq) ^ (r & 7);
                bfr[ni] = *(const bf16x8*)(ldsB + (r * 8 + g) * 8);
            }
#pragma unroll
            for (int mi = 0; mi < 4; ++mi)
#pragma unroll
                for (int ni = 0; ni < 4; ++ni)
                    acc[mi][ni] = __builtin_amdgcn_mfma_f32_16x16x32_bf16(
                        af[mi], bfr[ni], acc[mi][ni], 0, 0, 0);
        }
    }

    // scatter targets for MODE 1 (block-uniform region: bn<4 -> s, bn>=8 -> o)
    unsigned sc[4][4];
    if (MODE == 1 && (bn < 4 || bn >= 8)) {
#pragma unroll
        for (int mi = 0; mi < 4; ++mi)
#pragma unroll
            for (int r = 0; r < 4; ++r) {
                int grow = bm * 128 + wr + mi * 16 + lq * 4 + r;
                int b = grow >> 9;
                int idx = ((bn < 4) ? edges[grow * 3 + 0] : edges[grow * 3 + 2]) & 255;
                sc[mi][r] = (unsigned)(b * 256 + idx) * 512u;
            }
    }

    // epilogue: D row = (lane>>4)*4 + reg, col = lane&15  [m89/m91 layout]
#pragma unroll
    for (int ni = 0; ni < 4; ++ni) {
        int col = bn * 128 + wc + ni * 16 + lr;
        float bv = bias[col];
#pragma unroll
        for (int mi = 0; mi < 4; ++mi) {
            int rowb = bm * 128 + wr + mi * 16 + lq * 4;
            f32x4 v = acc[mi][ni];
#pragma unroll
            for (int r = 0; r < 4; r++) {
                float x = v[r] + bv;
                x = x > 0.f ? x : 0.f;
                int grow = rowb + r;
                if (MODE == 1) {
                    if (col < 512)       atomicAdd(pooledP + sc[mi][r] + col, x);
                    else if (col < 1024) Df[grow * 512 + (col - 512)] = x;
                    else                 atomicAdd(pooledP + sc[mi][r] + (col - 1024), x);
                } else if (MODE == 3) {
                    Df[grow * 512 + col] = x;
                } else {
                    Dbf[grow * 512 + col] = (bf16)x;
                }
            }
        }
    }
}

// f32 -> bf16 elementwise, 4 per thread
__global__ void cvt_k(const float4* __restrict__ s, bf16x4* __restrict__ d) {
    int i = blockIdx.x * 256 + threadIdx.x;
    float4 v = s[i];
    bf16x4 o = { (bf16)v.x, (bf16)v.y, (bf16)v.z, (bf16)v.w };
    d[i] = o;
}

// f32 src (R x C) -> bf16 dst (C x R)
__global__ void transpose_k(const float* __restrict__ src, bf16* __restrict__ dst,
                            int R, int C) {
    __shared__ float tile[32][33];
    int c0 = blockIdx.x * 32, r0 = blockIdx.y * 32;
    int tx = threadIdx.x, ty = threadIdx.y;  // (32,8)
#pragma unroll
    for (int i = 0; i < 4; i++)
        tile[ty + i * 8][tx] = src[(size_t)(r0 + ty + i * 8) * C + c0 + tx];
    __syncthreads();
#pragma unroll
    for (int i = 0; i < 4; i++)
        dst[(size_t)(c0 + ty + i * 8) * R + r0 + tx] = (bf16)tile[tx][ty + i * 8];
}

__global__ void zero_k(float4* __restrict__ p) {
    p[blockIdx.x * 256 + threadIdx.x] = make_float4(0.f, 0.f, 0.f, 0.f);
}

__global__ void counts_k(const int* __restrict__ edges, float* __restrict__ counts) {
    int e = blockIdx.x * 256 + threadIdx.x;  // 32768 edges
    int b = e >> 9;
    atomicAdd(counts + b * 256 + (edges[e * 3 + 0] & 255), 1.0f);
    atomicAdd(counts + b * 256 + (edges[e * 3 + 2] & 255), 1.0f);
}

__global__ void norm_k(const float* __restrict__ pooled,
                       const float* __restrict__ counts, bf16* __restrict__ out) {
    int i = blockIdx.x * 256 + threadIdx.x;  // 16384*512 total
    float c = counts[i >> 9];
    c = c > 1.f ? c : 1.f;
    out[i] = (bf16)(pooled[i] / c);
}

extern "C" void kernel_launch(void* const* d_in, const int* in_sizes, int n_in,
                              void* d_out, int out_size, void* d_ws, size_t ws_size,
                              hipStream_t stream) {
    // reference dtypes: all tensors float32, edges int (int32 in harness)
    const float* obj_f  = (const float*)d_in[0];
    const float* pred_f = (const float*)d_in[1];
    const int*   edges  = (const int*)d_in[2];
    const float* w1 = (const float*)d_in[3];
    const float* b1 = (const float*)d_in[4];
    const float* w2 = (const float*)d_in[5];
    const float* b2 = (const float*)d_in[6];
    const float* w3 = (const float*)d_in[7];
    const float* b3 = (const float*)d_in[8];
    const float* w4 = (const float*)d_in[9];
    const float* b4 = (const float*)d_in[10];

    // workspace layout — total 88,145,920 B (84.06 MB)
    char* ws = (char*)d_ws;
    bf16*  obj_bf  = (bf16*)(ws + 0);           // 64*256*512 bf16 (16 MB)
    bf16*  pred_bf = (bf16*)(ws + 16777216);    // 64*512*512 bf16 (32 MB)
    float* pooled  = (float*)(ws + 16777216);   // 16384 x 512 f32 — ALIAS pred_bf,
                                                // zeroed only after gemm1
    float* counts  = (float*)(ws + 50331648);   // 16384 f32, adjacent to pooled
    bf16* w1t = (bf16*)(ws + 50397184);         // 512 x 1536 bf16
    bf16* w2t = (bf16*)(ws + 51970048);         // 1536 x 512 bf16
    bf16* w3t = (bf16*)(ws + 53542912);         // 512 x 512 bf16
    bf16* w4t = (bf16*)(ws + 54067200);         // 512 x 512 bf16
    bf16* hid = (bf16*)(ws + 54591488);         // 32768 x 512 bf16 (32 MB)
    bf16* pooled_bf = hid;                      // 16384x512 — hid dead after gemm2
    bf16* h2  = (bf16*)(ws + 71368704);         // 16384x512 — upper half of hid

    float* out_obj = (float*)d_out;             // 64*256*512 f32
    float* out_p   = (float*)d_out + 8388608;   // 64*512*512 f32

    // front-end: f32 -> bf16 conversions
    cvt_k<<<8192, 256, 0, stream>>>((const float4*)obj_f, (bf16x4*)obj_bf);
    cvt_k<<<16384, 256, 0, stream>>>((const float4*)pred_f, (bf16x4*)pred_bf);
    transpose_k<<<dim3(16, 48), dim3(32, 8), 0, stream>>>(w1, w1t, 1536, 512);
    transpose_k<<<dim3(48, 16), dim3(32, 8), 0, stream>>>(w2, w2t, 512, 1536);
    transpose_k<<<dim3(16, 16), dim3(32, 8), 0, stream>>>(w3, w3t, 512, 512);
    transpose_k<<<dim3(16, 16), dim3(32, 8), 0, stream>>>(w4, w4t, 512, 512);

    gemm_k<0><<<dim3(256, 4), 256, 0, stream>>>(
        nullptr, w1t, b1, hid, nullptr, edges, obj_bf, pred_bf, nullptr, 1536);

    // pooled aliases pred_bf: zero only now (pred_bf dead after gemm1)
    zero_k<<<8208, 256, 0, stream>>>((float4*)pooled);  // pooled + counts
    counts_k<<<128, 256, 0, stream>>>(edges, counts);

    gemm_k<1><<<dim3(256, 12), 256, 0, stream>>>(
        hid, w2t, b2, nullptr, out_p, edges, nullptr, nullptr, pooled, 512);
    norm_k<<<32768, 256, 0, stream>>>(pooled, counts, pooled_bf);
    gemm_k<2><<<dim3(128, 4), 256, 0, stream>>>(
        pooled_bf, w3t, b3, h2, nullptr, nullptr, nullptr, nullptr, nullptr, 512);
    gemm_k<3><<<dim3(128, 4), 256, 0, stream>>>(
        h2, w4t, b4, nullptr, out_obj, nullptr, nullptr, nullptr, nullptr, 512);
}

// Round 4
// 428.226 us; speedup vs baseline: 1.1254x; 1.1254x over previous
//
#include <hip/hip_runtime.h>

typedef __bf16 bf16;
typedef __attribute__((ext_vector_type(4))) __bf16 bf16x4;
typedef __attribute__((ext_vector_type(8))) __bf16 bf16x8;
typedef __attribute__((ext_vector_type(4))) float f32x4;

#define DEVINL __device__ __forceinline__

typedef __attribute__((address_space(1))) void gvoid_t;
typedef __attribute__((address_space(3))) void lvoid_t;

DEVINL void async_ld16(const void* g, void* l) {
    __builtin_amdgcn_global_load_lds((gvoid_t*)g, (lvoid_t*)l, 16, 0, 0);
}

// C(M x N) = relu(A(M x K) @ Bt^T + bias); A,Bt bf16; bias f32.
// 128x128 tile, BK=64, 256 threads = 4 waves (2x2 of 64x64), 16x16x32 bf16 MFMA.
// MODE 0: A gathered from obj/pred via edges (K=1536, S|P|O), out -> Dbf (hid)
// MODE 1: split: col<512 -> Dbf(new_s,bf16); <1024 -> Df(out_p,f32); else Dbf2(new_o,bf16)
// MODE 2: plain -> Dbf.  MODE 3: plain -> Df (f32)
template<int MODE>
__global__ __launch_bounds__(256, 2) void gemm_k(
    const bf16* __restrict__ A, const bf16* __restrict__ Bt,
    const float* __restrict__ bias, bf16* __restrict__ Dbf,
    float* __restrict__ Df, bf16* __restrict__ Dbf2,
    const int* __restrict__ edges, const bf16* __restrict__ obj,
    const bf16* __restrict__ pred, int K)
{
    const int tid = threadIdx.x;
    const int bm = blockIdx.x;
    const int bn = blockIdx.y;

    __shared__ __align__(16) bf16 ldsA[128 * 64];
    __shared__ __align__(16) bf16 ldsB[128 * 64];

    // staging: thread covers granule flat = tid + 256*i -> row flat>>3, slot tid&7
    const int g_slot = tid & 7;
    const int row0 = tid >> 3;

    unsigned offS[4], offP[4], offO[4], offA[4], offB[4];
#pragma unroll
    for (int i = 0; i < 4; i++) {
        int r = row0 + 32 * i;
        int gr = bm * 128 + r;
        if (MODE == 0) {
            int b = gr >> 9;  // T = 512
            int s = edges[gr * 3 + 0] & 255;
            int o = edges[gr * 3 + 2] & 255;
            offS[i] = (unsigned)(b * 256 + s) * 512u;
            offP[i] = (unsigned)gr * 512u;
            offO[i] = (unsigned)(b * 256 + o) * 512u;
        } else {
            offA[i] = (unsigned)gr * (unsigned)K;
        }
        offB[i] = (unsigned)(bn * 128 + r) * (unsigned)K;
    }

    f32x4 acc[4][4];
    const f32x4 zero4 = {0.f, 0.f, 0.f, 0.f};
#pragma unroll
    for (int i = 0; i < 4; i++)
#pragma unroll
        for (int j = 0; j < 4; j++) acc[i][j] = zero4;

    const int wave = tid >> 6;
    const int lane = tid & 63;
    const int wr = (wave >> 1) * 64;
    const int wc = (wave & 1) * 64;
    const int lq = lane >> 4;
    const int lr = lane & 15;

    const int KT = K >> 6;
    for (int kt = 0; kt < KT; ++kt) {
        __syncthreads();  // prior iter's LDS reads complete in all waves
        // stage A: LDS slot (r, g_slot) holds global granule g_slot^(r&7)
#pragma unroll
        for (int i = 0; i < 4; i++) {
            int r = row0 + 32 * i;
            int gsrc = g_slot ^ (r & 7);
            const bf16* gp;
            if (MODE == 0) {
                int region = kt >> 3;  // wave-uniform
                unsigned col = (unsigned)((kt & 7) * 64 + gsrc * 8);
                if (region == 0)      gp = obj + offS[i] + col;
                else if (region == 1) gp = pred + offP[i] + col;
                else                  gp = obj + offO[i] + col;
            } else {
                gp = A + offA[i] + (unsigned)(kt * 64 + gsrc * 8);
            }
            async_ld16(gp, ldsA + (tid + i * 256) * 8);
        }
#pragma unroll
        for (int i = 0; i < 4; i++) {
            int r = row0 + 32 * i;
            int gsrc = g_slot ^ (r & 7);
            async_ld16(Bt + offB[i] + (unsigned)(kt * 64 + gsrc * 8),
                       ldsB + (tid + i * 256) * 8);
        }
        __syncthreads();  // vmcnt(0) drain -> tiles ready

#pragma unroll
        for (int ks = 0; ks < 2; ++ks) {
            bf16x8 af[4], bfr[4];
#pragma unroll
            for (int mi = 0; mi < 4; ++mi) {
                int r = wr + mi * 16 + lr;
                int g = (ks * 4 + lq) ^ (r & 7);
                af[mi] = *(const bf16x8*)(ldsA + (r * 8 + g) * 8);
            }
#pragma unroll
            for (int ni = 0; ni < 4; ++ni) {
                int r = wc + ni * 16 + lr;
                int g = (ks * 4 + lq) ^ (r & 7);
                bfr[ni] = *(const bf16x8*)(ldsB + (r * 8 + g) * 8);
            }
#pragma unroll
            for (int mi = 0; mi < 4; ++mi)
#pragma unroll
                for (int ni = 0; ni < 4; ++ni)
                    acc[mi][ni] = __builtin_amdgcn_mfma_f32_16x16x32_bf16(
                        af[mi], bfr[ni], acc[mi][ni], 0, 0, 0);
        }
    }

    // epilogue: D row = (lane>>4)*4 + reg, col = lane&15  [m89/m91 layout]
#pragma unroll
    for (int ni = 0; ni < 4; ++ni) {
        int col = bn * 128 + wc + ni * 16 + lr;
        float bv = bias[col];
#pragma unroll
        for (int mi = 0; mi < 4; ++mi) {
            int rowb = bm * 128 + wr + mi * 16 + lq * 4;
            f32x4 v = acc[mi][ni];
#pragma unroll
            for (int r = 0; r < 4; r++) {
                float x = v[r] + bv;
                x = x > 0.f ? x : 0.f;
                int grow = rowb + r;
                if (MODE == 1) {
                    if (col < 512)       Dbf[grow * 512 + col] = (bf16)x;
                    else if (col < 1024) Df[grow * 512 + (col - 512)] = x;
                    else                 Dbf2[grow * 512 + (col - 1024)] = (bf16)x;
                } else if (MODE == 3) {
                    Df[grow * 512 + col] = x;
                } else {
                    Dbf[grow * 512 + col] = (bf16)x;
                }
            }
        }
    }
}

// f32 -> bf16 elementwise, 4 per thread
__global__ void cvt_k(const float4* __restrict__ s, bf16x4* __restrict__ d) {
    int i = blockIdx.x * 256 + threadIdx.x;
    float4 v = s[i];
    bf16x4 o = { (bf16)v.x, (bf16)v.y, (bf16)v.z, (bf16)v.w };
    d[i] = o;
}

// f32 src (R x C) -> bf16 dst (C x R)
__global__ void transpose_k(const float* __restrict__ src, bf16* __restrict__ dst,
                            int R, int C) {
    __shared__ float tile[32][33];
    int c0 = blockIdx.x * 32, r0 = blockIdx.y * 32;
    int tx = threadIdx.x, ty = threadIdx.y;  // (32,8)
#pragma unroll
    for (int i = 0; i < 4; i++)
        tile[ty + i * 8][tx] = src[(size_t)(r0 + ty + i * 8) * C + c0 + tx];
    __syncthreads();
#pragma unroll
    for (int i = 0; i < 4; i++)
        dst[(size_t)(c0 + ty + i * 8) * R + r0 + tx] = (bf16)tile[tx][ty + i * 8];
}

// ---- CSR build over edges: 16384 nodes, exactly 1024 entries per batch ----
__global__ void zero_i4_k(int4* __restrict__ p) {  // 16 blocks: counts
    p[blockIdx.x * 256 + threadIdx.x] = make_int4(0, 0, 0, 0);
}

__global__ void count_k(const int* __restrict__ edges, int* __restrict__ counts) {
    int e = blockIdx.x * 256 + threadIdx.x;  // 32768 edges
    int b = e >> 9;
    atomicAdd(counts + b * 256 + (edges[e * 3 + 0] & 255), 1);
    atomicAdd(counts + b * 256 + (edges[e * 3 + 2] & 255), 1);
}

// per-batch exclusive scan of 256 counts -> starts & cursor (base b*1024)
__global__ void scan_k(const int* __restrict__ counts, int* __restrict__ starts,
                       int* __restrict__ cursor) {
    __shared__ int s[256];
    int b = blockIdx.x, t = threadIdx.x;
    int idx = b * 256 + t;
    int c0 = counts[idx];
    s[t] = c0;
    __syncthreads();
#pragma unroll
    for (int off = 1; off < 256; off <<= 1) {
        int v = (t >= off) ? s[t - off] : 0;
        __syncthreads();
        s[t] += v;
        __syncthreads();
    }
    int excl = b * 1024 + s[t] - c0;
    starts[idx] = excl;
    cursor[idx] = excl;
}

__global__ void fill_k(const int* __restrict__ edges, int* __restrict__ cursor,
                       int* __restrict__ entries) {
    int e = blockIdx.x * 256 + threadIdx.x;  // global edge row id
    int b = e >> 9;
    int s = edges[e * 3 + 0] & 255;
    int o = edges[e * 3 + 2] & 255;
    int ps = atomicAdd(cursor + b * 256 + s, 1);
    entries[ps] = e << 1;
    int po = atomicAdd(cursor + b * 256 + o, 1);
    entries[po] = (e << 1) | 1;
}

// gather-mean: block per (b,n); entry = rowid<<1 | (0=new_s, 1=new_o)
__global__ void pool_k(const int* __restrict__ entries, const int* __restrict__ starts,
                       const int* __restrict__ counts,
                       const bf16* __restrict__ new_s, const bf16* __restrict__ new_o,
                       bf16* __restrict__ out) {
    __shared__ int ent[1024];
    int idx = blockIdx.x;
    int t = threadIdx.x;
    int c = counts[idx], st = starts[idx];
    for (int j = t; j < c; j += 256) ent[j] = entries[st + j];
    __syncthreads();
    float a0 = 0.f, a1 = 0.f;
    for (int j = 0; j < c; ++j) {
        int v = ent[j];
        const bf16* rp = ((v & 1) ? new_o : new_s) + (unsigned)(v >> 1) * 512u;
        a0 += (float)rp[t];
        a1 += (float)rp[t + 256];
    }
    float inv = 1.f / (float)(c > 1 ? c : 1);
    out[(unsigned)idx * 512u + t]       = (bf16)(a0 * inv);
    out[(unsigned)idx * 512u + t + 256] = (bf16)(a1 * inv);
}

extern "C" void kernel_launch(void* const* d_in, const int* in_sizes, int n_in,
                              void* d_out, int out_size, void* d_ws, size_t ws_size,
                              hipStream_t stream) {
    const float* obj_f  = (const float*)d_in[0];
    const float* pred_f = (const float*)d_in[1];
    const int*   edges  = (const int*)d_in[2];
    const float* w1 = (const float*)d_in[3];
    const float* b1 = (const float*)d_in[4];
    const float* w2 = (const float*)d_in[5];
    const float* b2 = (const float*)d_in[6];
    const float* w3 = (const float*)d_in[7];
    const float* b3 = (const float*)d_in[8];
    const float* w4 = (const float*)d_in[9];
    const float* b4 = (const float*)d_in[10];

    // workspace layout — total 88,080,384 B (84 MB)
    char* ws = (char*)d_ws;
    bf16* obj_bf  = (bf16*)(ws + 0);            // 16 MB   [dead after gemm1]
    bf16* pred_bf = (bf16*)(ws + 16777216);     // 32 MB   [dead after gemm1]
    bf16* new_s   = (bf16*)(ws + 0);            // 32 MB   overlays obj/pred
    int* entries  = (int*)(ws + 33554432);      // 256 KB  (32-48M zone, free post-gemm1)
    int* counts   = (int*)(ws + 33816576);      // 64 KB
    int* starts   = (int*)(ws + 33882112);      // 64 KB
    int* cursor   = (int*)(ws + 33947648);      // 64 KB
    bf16* w1t = (bf16*)(ws + 50331648);         // 512 x 1536
    bf16* w2t = (bf16*)(ws + 51904512);         // 1536 x 512
    bf16* w3t = (bf16*)(ws + 53477376);         // 512 x 512
    bf16* w4t = (bf16*)(ws + 54001664);         // 512 x 512
    bf16* hid = (bf16*)(ws + 54525952);         // 32768 x 512 (32 MB) [dead after gemm2]
    bf16* pooled_bf = hid;                      // 16 MB, reuse after gemm2
    bf16* h2  = (bf16*)(ws + 71303168);         // 16 MB, upper half of hid

    float* out_obj = (float*)d_out;             // 64*256*512 f32 (33.5 MB)
    float* out_p   = (float*)d_out + 8388608;   // 64*512*512 f32
    bf16* new_o    = (bf16*)d_out;              // 32 MB scratch in out_obj region;
                                                // overwritten by gemm4 at the end

    cvt_k<<<8192, 256, 0, stream>>>((const float4*)obj_f, (bf16x4*)obj_bf);
    cvt_k<<<16384, 256, 0, stream>>>((const float4*)pred_f, (bf16x4*)pred_bf);
    transpose_k<<<dim3(16, 48), dim3(32, 8), 0, stream>>>(w1, w1t, 1536, 512);
    transpose_k<<<dim3(48, 16), dim3(32, 8), 0, stream>>>(w2, w2t, 512, 1536);
    transpose_k<<<dim3(16, 16), dim3(32, 8), 0, stream>>>(w3, w3t, 512, 512);
    transpose_k<<<dim3(16, 16), dim3(32, 8), 0, stream>>>(w4, w4t, 512, 512);

    gemm_k<0><<<dim3(256, 4), 256, 0, stream>>>(
        nullptr, w1t, b1, hid, nullptr, nullptr, edges, obj_bf, pred_bf, 1536);

    // CSR build (32-48M zone free now; tiny kernels)
    zero_i4_k<<<16, 256, 0, stream>>>((int4*)counts);
    count_k<<<128, 256, 0, stream>>>(edges, counts);
    scan_k<<<64, 256, 0, stream>>>(counts, starts, cursor);
    fill_k<<<128, 256, 0, stream>>>(edges, cursor, entries);

    gemm_k<1><<<dim3(256, 12), 256, 0, stream>>>(
        hid, w2t, b2, new_s, out_p, new_o, nullptr, nullptr, nullptr, 512);

    pool_k<<<16384, 256, 0, stream>>>(entries, starts, counts, new_s, new_o, pooled_bf);

    gemm_k<2><<<dim3(128, 4), 256, 0, stream>>>(
        pooled_bf, w3t, b3, h2, nullptr, nullptr, nullptr, nullptr, nullptr, 512);
    gemm_k<3><<<dim3(128, 4), 256, 0, stream>>>(
        h2, w4t, b4, nullptr, out_obj, nullptr, nullptr, nullptr, nullptr, 512);
}

// Round 5
// 425.703 us; speedup vs baseline: 1.1321x; 1.0059x over previous
//
#include <hip/hip_runtime.h>

typedef __bf16 bf16;
typedef __attribute__((ext_vector_type(4))) __bf16 bf16x4;
typedef __attribute__((ext_vector_type(8))) __bf16 bf16x8;
typedef __attribute__((ext_vector_type(4))) float f32x4;

#define DEVINL __device__ __forceinline__

typedef __attribute__((address_space(1))) void gvoid_t;
typedef __attribute__((address_space(3))) void lvoid_t;

DEVINL void async_ld16(const void* g, void* l) {
    __builtin_amdgcn_global_load_lds((gvoid_t*)g, (lvoid_t*)l, 16, 0, 0);
}

// C(M x N) = relu(A(M x K) @ Bt^T + bias); A,Bt bf16; bias f32.
// 128x128 tile, BK=64, 256 threads = 4 waves (2x2 of 64x64), 16x16x32 bf16 MFMA.
// OPERANDS SWAPPED: mfma(bfr, af) computes C^T fragments -> lane holds
// row = lane&15 (M in lanes), cols = quad*4 + reg (4 consecutive N in regs)
// => vectorized epilogue stores (f32x4 = 16B, bf16x4 = 8B per lane).
// Grid: blockIdx.x = bn (fast) so same-bm blocks share A in L2.
// MODE 0: A gathered from obj/pred via edges (K=1536, S|P|O), out -> Dbf (hid)
// MODE 1: split: col<512 -> Dbf(new_s,bf16); <1024 -> Df(out_p,f32); else Dbf2(new_o,bf16)
// MODE 2: plain -> Dbf.  MODE 3: plain -> Df (f32)
template<int MODE>
__global__ __launch_bounds__(256, 2) void gemm_k(
    const bf16* __restrict__ A, const bf16* __restrict__ Bt,
    const float* __restrict__ bias, bf16* __restrict__ Dbf,
    float* __restrict__ Df, bf16* __restrict__ Dbf2,
    const int* __restrict__ edges, const bf16* __restrict__ obj,
    const bf16* __restrict__ pred, int K)
{
    const int tid = threadIdx.x;
    const int bn = blockIdx.x;   // fast dim: blocks sharing A run together
    const int bm = blockIdx.y;

    __shared__ __align__(16) bf16 ldsA[128 * 64];
    __shared__ __align__(16) bf16 ldsB[128 * 64];

    // staging: thread covers granule flat = tid + 256*i -> row flat>>3, slot tid&7
    const int g_slot = tid & 7;
    const int row0 = tid >> 3;

    unsigned offS[4], offP[4], offO[4], offA[4], offB[4];
#pragma unroll
    for (int i = 0; i < 4; i++) {
        int r = row0 + 32 * i;
        int gr = bm * 128 + r;
        if (MODE == 0) {
            int b = gr >> 9;  // T = 512
            int s = edges[gr * 3 + 0] & 255;
            int o = edges[gr * 3 + 2] & 255;
            offS[i] = (unsigned)(b * 256 + s) * 512u;
            offP[i] = (unsigned)gr * 512u;
            offO[i] = (unsigned)(b * 256 + o) * 512u;
        } else {
            offA[i] = (unsigned)gr * (unsigned)K;
        }
        offB[i] = (unsigned)(bn * 128 + r) * (unsigned)K;
    }

    f32x4 acc[4][4];
    const f32x4 zero4 = {0.f, 0.f, 0.f, 0.f};
#pragma unroll
    for (int i = 0; i < 4; i++)
#pragma unroll
        for (int j = 0; j < 4; j++) acc[i][j] = zero4;

    const int wave = tid >> 6;
    const int lane = tid & 63;
    const int wr = (wave >> 1) * 64;
    const int wc = (wave & 1) * 64;
    const int lq = lane >> 4;
    const int lr = lane & 15;

    const int KT = K >> 6;
    for (int kt = 0; kt < KT; ++kt) {
        __syncthreads();  // prior iter's LDS reads complete in all waves
        // stage A: LDS slot (r, g_slot) holds global granule g_slot^(r&7)
#pragma unroll
        for (int i = 0; i < 4; i++) {
            int r = row0 + 32 * i;
            int gsrc = g_slot ^ (r & 7);
            const bf16* gp;
            if (MODE == 0) {
                int region = kt >> 3;  // wave-uniform
                unsigned col = (unsigned)((kt & 7) * 64 + gsrc * 8);
                if (region == 0)      gp = obj + offS[i] + col;
                else if (region == 1) gp = pred + offP[i] + col;
                else                  gp = obj + offO[i] + col;
            } else {
                gp = A + offA[i] + (unsigned)(kt * 64 + gsrc * 8);
            }
            async_ld16(gp, ldsA + (tid + i * 256) * 8);
        }
#pragma unroll
        for (int i = 0; i < 4; i++) {
            int r = row0 + 32 * i;
            int gsrc = g_slot ^ (r & 7);
            async_ld16(Bt + offB[i] + (unsigned)(kt * 64 + gsrc * 8),
                       ldsB + (tid + i * 256) * 8);
        }
        __syncthreads();  // vmcnt(0) drain -> tiles ready

#pragma unroll
        for (int ks = 0; ks < 2; ++ks) {
            bf16x8 af[4], bfr[4];
#pragma unroll
            for (int mi = 0; mi < 4; ++mi) {
                int r = wr + mi * 16 + lr;
                int g = (ks * 4 + lq) ^ (r & 7);
                af[mi] = *(const bf16x8*)(ldsA + (r * 8 + g) * 8);
            }
#pragma unroll
            for (int ni = 0; ni < 4; ++ni) {
                int r = wc + ni * 16 + lr;
                int g = (ks * 4 + lq) ^ (r & 7);
                bfr[ni] = *(const bf16x8*)(ldsB + (r * 8 + g) * 8);
            }
            // SWAPPED operands: D = Bt_frag x A_frag = C^T fragments
#pragma unroll
            for (int mi = 0; mi < 4; ++mi)
#pragma unroll
                for (int ni = 0; ni < 4; ++ni)
                    acc[mi][ni] = __builtin_amdgcn_mfma_f32_16x16x32_bf16(
                        bfr[ni], af[mi], acc[mi][ni], 0, 0, 0);
        }
    }

    // epilogue (swapped layout): row(M) = wr+mi*16+lr, cols(N) = wc+ni*16+lq*4+[0,4)
#pragma unroll
    for (int ni = 0; ni < 4; ++ni) {
        int col = bn * 128 + wc + ni * 16 + lq * 4;
        const f32x4 bv = *(const f32x4*)(bias + col);
#pragma unroll
        for (int mi = 0; mi < 4; ++mi) {
            int row = bm * 128 + wr + mi * 16 + lr;
            f32x4 v = acc[mi][ni];
            f32x4 x;
#pragma unroll
            for (int r = 0; r < 4; r++) {
                float t = v[r] + bv[r];
                x[r] = t > 0.f ? t : 0.f;
            }
            if (MODE == 1) {
                if (col < 512) {
                    bf16x4 o = { (bf16)x[0], (bf16)x[1], (bf16)x[2], (bf16)x[3] };
                    *(bf16x4*)(Dbf + row * 512 + col) = o;
                } else if (col < 1024) {
                    *(f32x4*)(Df + row * 512 + (col - 512)) = x;
                } else {
                    bf16x4 o = { (bf16)x[0], (bf16)x[1], (bf16)x[2], (bf16)x[3] };
                    *(bf16x4*)(Dbf2 + row * 512 + (col - 1024)) = o;
                }
            } else if (MODE == 3) {
                *(f32x4*)(Df + row * 512 + col) = x;
            } else {
                bf16x4 o = { (bf16)x[0], (bf16)x[1], (bf16)x[2], (bf16)x[3] };
                *(bf16x4*)(Dbf + row * 512 + col) = o;
            }
        }
    }
}

// f32 -> bf16 elementwise, 4 per thread
__global__ void cvt_k(const float4* __restrict__ s, bf16x4* __restrict__ d) {
    int i = blockIdx.x * 256 + threadIdx.x;
    float4 v = s[i];
    bf16x4 o = { (bf16)v.x, (bf16)v.y, (bf16)v.z, (bf16)v.w };
    d[i] = o;
}

// f32 src (R x C) -> bf16 dst (C x R)
__global__ void transpose_k(const float* __restrict__ src, bf16* __restrict__ dst,
                            int R, int C) {
    __shared__ float tile[32][33];
    int c0 = blockIdx.x * 32, r0 = blockIdx.y * 32;
    int tx = threadIdx.x, ty = threadIdx.y;  // (32,8)
#pragma unroll
    for (int i = 0; i < 4; i++)
        tile[ty + i * 8][tx] = src[(size_t)(r0 + ty + i * 8) * C + c0 + tx];
    __syncthreads();
#pragma unroll
    for (int i = 0; i < 4; i++)
        dst[(size_t)(c0 + ty + i * 8) * R + r0 + tx] = (bf16)tile[tx][ty + i * 8];
}

// ---- CSR build over edges: 16384 nodes, exactly 1024 entries per batch ----
__global__ void zero_i4_k(int4* __restrict__ p) {  // 16 blocks: counts
    p[blockIdx.x * 256 + threadIdx.x] = make_int4(0, 0, 0, 0);
}

__global__ void count_k(const int* __restrict__ edges, int* __restrict__ counts) {
    int e = blockIdx.x * 256 + threadIdx.x;  // 32768 edges
    int b = e >> 9;
    atomicAdd(counts + b * 256 + (edges[e * 3 + 0] & 255), 1);
    atomicAdd(counts + b * 256 + (edges[e * 3 + 2] & 255), 1);
}

// per-batch exclusive scan of 256 counts -> starts & cursor (base b*1024)
__global__ void scan_k(const int* __restrict__ counts, int* __restrict__ starts,
                       int* __restrict__ cursor) {
    __shared__ int s[256];
    int b = blockIdx.x, t = threadIdx.x;
    int idx = b * 256 + t;
    int c0 = counts[idx];
    s[t] = c0;
    __syncthreads();
#pragma unroll
    for (int off = 1; off < 256; off <<= 1) {
        int v = (t >= off) ? s[t - off] : 0;
        __syncthreads();
        s[t] += v;
        __syncthreads();
    }
    int excl = b * 1024 + s[t] - c0;
    starts[idx] = excl;
    cursor[idx] = excl;
}

__global__ void fill_k(const int* __restrict__ edges, int* __restrict__ cursor,
                       int* __restrict__ entries) {
    int e = blockIdx.x * 256 + threadIdx.x;  // global edge row id
    int b = e >> 9;
    int s = edges[e * 3 + 0] & 255;
    int o = edges[e * 3 + 2] & 255;
    int ps = atomicAdd(cursor + b * 256 + s, 1);
    entries[ps] = e << 1;
    int po = atomicAdd(cursor + b * 256 + o, 1);
    entries[po] = (e << 1) | 1;
}

// gather-mean: block per (b,n); entry = rowid<<1 | (0=new_s, 1=new_o)
__global__ void pool_k(const int* __restrict__ entries, const int* __restrict__ starts,
                       const int* __restrict__ counts,
                       const bf16* __restrict__ new_s, const bf16* __restrict__ new_o,
                       bf16* __restrict__ out) {
    __shared__ int ent[1024];
    int idx = blockIdx.x;
    int t = threadIdx.x;
    int c = counts[idx], st = starts[idx];
    for (int j = t; j < c; j += 256) ent[j] = entries[st + j];
    __syncthreads();
    float a0 = 0.f, a1 = 0.f;
    for (int j = 0; j < c; ++j) {
        int v = ent[j];
        const bf16* rp = ((v & 1) ? new_o : new_s) + (unsigned)(v >> 1) * 512u;
        a0 += (float)rp[t];
        a1 += (float)rp[t + 256];
    }
    float inv = 1.f / (float)(c > 1 ? c : 1);
    out[(unsigned)idx * 512u + t]       = (bf16)(a0 * inv);
    out[(unsigned)idx * 512u + t + 256] = (bf16)(a1 * inv);
}

extern "C" void kernel_launch(void* const* d_in, const int* in_sizes, int n_in,
                              void* d_out, int out_size, void* d_ws, size_t ws_size,
                              hipStream_t stream) {
    const float* obj_f  = (const float*)d_in[0];
    const float* pred_f = (const float*)d_in[1];
    const int*   edges  = (const int*)d_in[2];
    const float* w1 = (const float*)d_in[3];
    const float* b1 = (const float*)d_in[4];
    const float* w2 = (const float*)d_in[5];
    const float* b2 = (const float*)d_in[6];
    const float* w3 = (const float*)d_in[7];
    const float* b3 = (const float*)d_in[8];
    const float* w4 = (const float*)d_in[9];
    const float* b4 = (const float*)d_in[10];

    // workspace layout — total 88,080,384 B (84 MB)
    char* ws = (char*)d_ws;
    bf16* obj_bf  = (bf16*)(ws + 0);            // 16 MB   [dead after gemm1]
    bf16* pred_bf = (bf16*)(ws + 16777216);     // 32 MB   [dead after gemm1]
    bf16* new_s   = (bf16*)(ws + 0);            // 32 MB   overlays obj/pred
    int* entries  = (int*)(ws + 33554432);      // 256 KB  (32-48M zone, free post-gemm1)
    int* counts   = (int*)(ws + 33816576);      // 64 KB
    int* starts   = (int*)(ws + 33882112);      // 64 KB
    int* cursor   = (int*)(ws + 33947648);      // 64 KB
    bf16* w1t = (bf16*)(ws + 50331648);         // 512 x 1536
    bf16* w2t = (bf16*)(ws + 51904512);         // 1536 x 512
    bf16* w3t = (bf16*)(ws + 53477376);         // 512 x 512
    bf16* w4t = (bf16*)(ws + 54001664);         // 512 x 512
    bf16* hid = (bf16*)(ws + 54525952);         // 32768 x 512 (32 MB) [dead after gemm2]
    bf16* pooled_bf = hid;                      // 16 MB, reuse after gemm2
    bf16* h2  = (bf16*)(ws + 71303168);         // 16 MB, upper half of hid

    float* out_obj = (float*)d_out;             // 64*256*512 f32 (33.5 MB)
    float* out_p   = (float*)d_out + 8388608;   // 64*512*512 f32
    bf16* new_o    = (bf16*)d_out;              // 32 MB scratch in out_obj region;
                                                // overwritten by gemm4 at the end

    cvt_k<<<8192, 256, 0, stream>>>((const float4*)obj_f, (bf16x4*)obj_bf);
    cvt_k<<<16384, 256, 0, stream>>>((const float4*)pred_f, (bf16x4*)pred_bf);
    transpose_k<<<dim3(16, 48), dim3(32, 8), 0, stream>>>(w1, w1t, 1536, 512);
    transpose_k<<<dim3(48, 16), dim3(32, 8), 0, stream>>>(w2, w2t, 512, 1536);
    transpose_k<<<dim3(16, 16), dim3(32, 8), 0, stream>>>(w3, w3t, 512, 512);
    transpose_k<<<dim3(16, 16), dim3(32, 8), 0, stream>>>(w4, w4t, 512, 512);

    gemm_k<0><<<dim3(4, 256), 256, 0, stream>>>(
        nullptr, w1t, b1, hid, nullptr, nullptr, edges, obj_bf, pred_bf, 1536);

    // CSR build (32-48M zone free now; tiny kernels)
    zero_i4_k<<<16, 256, 0, stream>>>((int4*)counts);
    count_k<<<128, 256, 0, stream>>>(edges, counts);
    scan_k<<<64, 256, 0, stream>>>(counts, starts, cursor);
    fill_k<<<128, 256, 0, stream>>>(edges, cursor, entries);

    gemm_k<1><<<dim3(12, 256), 256, 0, stream>>>(
        hid, w2t, b2, new_s, out_p, new_o, nullptr, nullptr, nullptr, 512);

    pool_k<<<16384, 256, 0, stream>>>(entries, starts, counts, new_s, new_o, pooled_bf);

    gemm_k<2><<<dim3(4, 128), 256, 0, stream>>>(
        pooled_bf, w3t, b3, h2, nullptr, nullptr, nullptr, nullptr, nullptr, 512);
    gemm_k<3><<<dim3(4, 128), 256, 0, stream>>>(
        h2, w4t, b4, nullptr, out_obj, nullptr, nullptr, nullptr, nullptr, 512);
}

// Round 6
// 389.327 us; speedup vs baseline: 1.2379x; 1.0934x over previous
//
#include <hip/hip_runtime.h>

typedef __bf16 bf16;
typedef __attribute__((ext_vector_type(4))) __bf16 bf16x4;
typedef __attribute__((ext_vector_type(8))) __bf16 bf16x8;
typedef __attribute__((ext_vector_type(4))) float f32x4;

#define DEVINL __device__ __forceinline__

typedef __attribute__((address_space(1))) void gvoid_t;
typedef __attribute__((address_space(3))) void lvoid_t;

DEVINL void async_ld16(const void* g, void* l) {
    __builtin_amdgcn_global_load_lds((gvoid_t*)g, (lvoid_t*)l, 16, 0, 0);
}

// C(M x N) = relu(A(M x K) @ Bt^T + bias); A,Bt bf16; bias f32.
// 128x128 tile, BK=64, 256 threads = 4 waves (2x2 of 64x64), 16x16x32 bf16 MFMA.
// Swapped operands: mfma(bfr, af) -> row(M)=lane&15 in lanes, 4 consecutive
// cols(N) in regs -> vectorized stores.
// 1-D grid + XCD swizzle: id&7 = XCD (round-robin dispatch), all NBN blocks of
// one bm-tile land on the SAME XCD so the A-tile is fetched once per XCD L2.
// MODE 0: A gathered from obj/pred via edges (K=1536, S|P|O), out -> Dbf (hid)
// MODE 1: split: col<512 -> Dbf(new_s); <1024 -> Df(out_p,f32); else Dbf2(new_o)
// MODE 2: plain -> Dbf.  MODE 3: plain -> Df (f32)
template<int MODE, int NBN>
__global__ __launch_bounds__(256, 2) void gemm_k(
    const bf16* __restrict__ A, const bf16* __restrict__ Bt,
    const float* __restrict__ bias, bf16* __restrict__ Dbf,
    float* __restrict__ Df, bf16* __restrict__ Dbf2,
    const int* __restrict__ edges, const bf16* __restrict__ obj,
    const bf16* __restrict__ pred, int K)
{
    const int tid = threadIdx.x;
    const int id = blockIdx.x;
    const int bn = (id >> 3) % NBN;
    const int bm = (id & 7) + 8 * ((id >> 3) / NBN);

    __shared__ __align__(16) bf16 ldsA[128 * 64];
    __shared__ __align__(16) bf16 ldsB[128 * 64];

    // staging: thread covers granule flat = tid + 256*i -> row flat>>3, slot tid&7
    const int g_slot = tid & 7;
    const int row0 = tid >> 3;

    unsigned offS[4], offP[4], offO[4], offA[4], offB[4];
#pragma unroll
    for (int i = 0; i < 4; i++) {
        int r = row0 + 32 * i;
        int gr = bm * 128 + r;
        if (MODE == 0) {
            int b = gr >> 9;  // T = 512
            int s = edges[gr * 3 + 0] & 255;
            int o = edges[gr * 3 + 2] & 255;
            offS[i] = (unsigned)(b * 256 + s) * 512u;
            offP[i] = (unsigned)gr * 512u;
            offO[i] = (unsigned)(b * 256 + o) * 512u;
        } else {
            offA[i] = (unsigned)gr * (unsigned)K;
        }
        offB[i] = (unsigned)(bn * 128 + r) * (unsigned)K;
    }

    f32x4 acc[4][4];
    const f32x4 zero4 = {0.f, 0.f, 0.f, 0.f};
#pragma unroll
    for (int i = 0; i < 4; i++)
#pragma unroll
        for (int j = 0; j < 4; j++) acc[i][j] = zero4;

    const int wave = tid >> 6;
    const int lane = tid & 63;
    const int wr = (wave >> 1) * 64;
    const int wc = (wave & 1) * 64;
    const int lq = lane >> 4;
    const int lr = lane & 15;

    const int KT = K >> 6;
    for (int kt = 0; kt < KT; ++kt) {
        __syncthreads();  // prior iter's LDS reads complete in all waves
        // stage A: LDS slot (r, g_slot) holds global granule g_slot^(r&7)
#pragma unroll
        for (int i = 0; i < 4; i++) {
            int r = row0 + 32 * i;
            int gsrc = g_slot ^ (r & 7);
            const bf16* gp;
            if (MODE == 0) {
                int region = kt >> 3;  // wave-uniform
                unsigned col = (unsigned)((kt & 7) * 64 + gsrc * 8);
                if (region == 0)      gp = obj + offS[i] + col;
                else if (region == 1) gp = pred + offP[i] + col;
                else                  gp = obj + offO[i] + col;
            } else {
                gp = A + offA[i] + (unsigned)(kt * 64 + gsrc * 8);
            }
            async_ld16(gp, ldsA + (tid + i * 256) * 8);
        }
#pragma unroll
        for (int i = 0; i < 4; i++) {
            int r = row0 + 32 * i;
            int gsrc = g_slot ^ (r & 7);
            async_ld16(Bt + offB[i] + (unsigned)(kt * 64 + gsrc * 8),
                       ldsB + (tid + i * 256) * 8);
        }
        __syncthreads();  // vmcnt(0) drain -> tiles ready

#pragma unroll
        for (int ks = 0; ks < 2; ++ks) {
            bf16x8 af[4], bfr[4];
#pragma unroll
            for (int mi = 0; mi < 4; ++mi) {
                int r = wr + mi * 16 + lr;
                int g = (ks * 4 + lq) ^ (r & 7);
                af[mi] = *(const bf16x8*)(ldsA + (r * 8 + g) * 8);
            }
#pragma unroll
            for (int ni = 0; ni < 4; ++ni) {
                int r = wc + ni * 16 + lr;
                int g = (ks * 4 + lq) ^ (r & 7);
                bfr[ni] = *(const bf16x8*)(ldsB + (r * 8 + g) * 8);
            }
            // swapped operands: D = Bt_frag x A_frag = C^T fragments
#pragma unroll
            for (int mi = 0; mi < 4; ++mi)
#pragma unroll
                for (int ni = 0; ni < 4; ++ni)
                    acc[mi][ni] = __builtin_amdgcn_mfma_f32_16x16x32_bf16(
                        bfr[ni], af[mi], acc[mi][ni], 0, 0, 0);
        }
    }

    // epilogue (swapped layout): row(M) = wr+mi*16+lr, cols(N) = wc+ni*16+lq*4+[0,4)
#pragma unroll
    for (int ni = 0; ni < 4; ++ni) {
        int col = bn * 128 + wc + ni * 16 + lq * 4;
        const f32x4 bv = *(const f32x4*)(bias + col);
#pragma unroll
        for (int mi = 0; mi < 4; ++mi) {
            int row = bm * 128 + wr + mi * 16 + lr;
            f32x4 v = acc[mi][ni];
            f32x4 x;
#pragma unroll
            for (int r = 0; r < 4; r++) {
                float t = v[r] + bv[r];
                x[r] = t > 0.f ? t : 0.f;
            }
            if (MODE == 1) {
                if (col < 512) {
                    bf16x4 o = { (bf16)x[0], (bf16)x[1], (bf16)x[2], (bf16)x[3] };
                    *(bf16x4*)(Dbf + row * 512 + col) = o;
                } else if (col < 1024) {
                    *(f32x4*)(Df + row * 512 + (col - 512)) = x;
                } else {
                    bf16x4 o = { (bf16)x[0], (bf16)x[1], (bf16)x[2], (bf16)x[3] };
                    *(bf16x4*)(Dbf2 + row * 512 + (col - 1024)) = o;
                }
            } else if (MODE == 3) {
                *(f32x4*)(Df + row * 512 + col) = x;
            } else {
                bf16x4 o = { (bf16)x[0], (bf16)x[1], (bf16)x[2], (bf16)x[3] };
                *(bf16x4*)(Dbf + row * 512 + col) = o;
            }
        }
    }
}

// fused f32 -> bf16 for obj (2,097,152 float4) + pred (4,194,304 float4)
__global__ void cvt2_k(const float4* __restrict__ o, const float4* __restrict__ p,
                       bf16x4* __restrict__ ob, bf16x4* __restrict__ pb) {
    int i = blockIdx.x * 256 + threadIdx.x;
    if (i < 2097152) {
        float4 v = o[i];
        bf16x4 r = { (bf16)v.x, (bf16)v.y, (bf16)v.z, (bf16)v.w };
        ob[i] = r;
    } else {
        int j = i - 2097152;
        float4 v = p[j];
        bf16x4 r = { (bf16)v.x, (bf16)v.y, (bf16)v.z, (bf16)v.w };
        pb[j] = r;
    }
}

// fused transpose of all 4 weights: f32 src (R x C) -> bf16 dst (C x R)
__global__ void transpose4_k(const float* __restrict__ w1, bf16* __restrict__ w1t,
                             const float* __restrict__ w2, bf16* __restrict__ w2t,
                             const float* __restrict__ w3, bf16* __restrict__ w3t,
                             const float* __restrict__ w4, bf16* __restrict__ w4t) {
    __shared__ float tile[32][33];
    int id = blockIdx.x;
    const float* src; bf16* dst; int R, C, bx, by;
    if (id < 768)       { src = w1; dst = w1t; R = 1536; C = 512;  bx = id % 16; by = id / 16; }
    else if (id < 1536) { id -= 768;  src = w2; dst = w2t; R = 512; C = 1536; bx = id % 48; by = id / 48; }
    else if (id < 1792) { id -= 1536; src = w3; dst = w3t; R = 512; C = 512;  bx = id % 16; by = id / 16; }
    else                { id -= 1792; src = w4; dst = w4t; R = 512; C = 512;  bx = id % 16; by = id / 16; }
    int c0 = bx * 32, r0 = by * 32;
    int tx = threadIdx.x, ty = threadIdx.y;  // (32,8)
#pragma unroll
    for (int i = 0; i < 4; i++)
        tile[ty + i * 8][tx] = src[(size_t)(r0 + ty + i * 8) * C + c0 + tx];
    __syncthreads();
#pragma unroll
    for (int i = 0; i < 4; i++)
        dst[(size_t)(c0 + ty + i * 8) * R + r0 + tx] = (bf16)tile[tx][ty + i * 8];
}

// fused CSR build: one block per batch, all in LDS (no global atomics).
// entries[b*1024 + pos] = rowid<<1 | (0=new_s, 1=new_o)
__global__ void csr_k(const int* __restrict__ edges, int* __restrict__ counts_g,
                      int* __restrict__ starts_g, int* __restrict__ entries) {
    __shared__ int cnt[256];
    __shared__ int s[256];
    __shared__ int cur[256];
    int b = blockIdx.x, t = threadIdx.x;
    cnt[t] = 0;
    __syncthreads();
#pragma unroll
    for (int e = 0; e < 2; e++) {
        int row = b * 512 + t + e * 256;
        atomicAdd(&cnt[edges[row * 3 + 0] & 255], 1);
        atomicAdd(&cnt[edges[row * 3 + 2] & 255], 1);
    }
    __syncthreads();
    int c0 = cnt[t];
    s[t] = c0;
    __syncthreads();
#pragma unroll
    for (int off = 1; off < 256; off <<= 1) {
        int v = (t >= off) ? s[t - off] : 0;
        __syncthreads();
        s[t] += v;
        __syncthreads();
    }
    int excl = s[t] - c0;
    counts_g[b * 256 + t] = c0;
    starts_g[b * 256 + t] = b * 1024 + excl;
    cur[t] = excl;
    __syncthreads();
#pragma unroll
    for (int e = 0; e < 2; e++) {
        int row = b * 512 + t + e * 256;
        int si = edges[row * 3 + 0] & 255;
        int oi = edges[row * 3 + 2] & 255;
        int ps = atomicAdd(&cur[si], 1);
        entries[b * 1024 + ps] = row << 1;
        int po = atomicAdd(&cur[oi], 1);
        entries[b * 1024 + po] = (row << 1) | 1;
    }
}

// gather-mean: block per (b,n); entry = rowid<<1 | (0=new_s, 1=new_o)
__global__ void pool_k(const int* __restrict__ entries, const int* __restrict__ starts,
                       const int* __restrict__ counts,
                       const bf16* __restrict__ new_s, const bf16* __restrict__ new_o,
                       bf16* __restrict__ out) {
    __shared__ int ent[1024];
    int idx = blockIdx.x;
    int t = threadIdx.x;
    int c = counts[idx], st = starts[idx];
    for (int j = t; j < c; j += 256) ent[j] = entries[st + j];
    __syncthreads();
    float a0 = 0.f, a1 = 0.f;
    for (int j = 0; j < c; ++j) {
        int v = ent[j];
        const bf16* rp = ((v & 1) ? new_o : new_s) + (unsigned)(v >> 1) * 512u;
        a0 += (float)rp[t];
        a1 += (float)rp[t + 256];
    }
    float inv = 1.f / (float)(c > 1 ? c : 1);
    out[(unsigned)idx * 512u + t]       = (bf16)(a0 * inv);
    out[(unsigned)idx * 512u + t + 256] = (bf16)(a1 * inv);
}

extern "C" void kernel_launch(void* const* d_in, const int* in_sizes, int n_in,
                              void* d_out, int out_size, void* d_ws, size_t ws_size,
                              hipStream_t stream) {
    const float* obj_f  = (const float*)d_in[0];
    const float* pred_f = (const float*)d_in[1];
    const int*   edges  = (const int*)d_in[2];
    const float* w1 = (const float*)d_in[3];
    const float* b1 = (const float*)d_in[4];
    const float* w2 = (const float*)d_in[5];
    const float* b2 = (const float*)d_in[6];
    const float* w3 = (const float*)d_in[7];
    const float* b3 = (const float*)d_in[8];
    const float* w4 = (const float*)d_in[9];
    const float* b4 = (const float*)d_in[10];

    // workspace layout — 84 MB
    char* ws = (char*)d_ws;
    bf16* obj_bf  = (bf16*)(ws + 0);            // 16 MB   [dead after gemm1]
    bf16* pred_bf = (bf16*)(ws + 16777216);     // 32 MB   [dead after gemm1]
    bf16* new_s   = (bf16*)(ws + 0);            // 32 MB   overlays obj/pred
    int* entries  = (int*)(ws + 33554432);      // 256 KB  (zone free post-gemm1)
    int* counts   = (int*)(ws + 33816576);      // 64 KB
    int* starts   = (int*)(ws + 33882112);      // 64 KB
    bf16* w1t = (bf16*)(ws + 50331648);         // 512 x 1536
    bf16* w2t = (bf16*)(ws + 51904512);         // 1536 x 512
    bf16* w3t = (bf16*)(ws + 53477376);         // 512 x 512
    bf16* w4t = (bf16*)(ws + 54001664);         // 512 x 512
    bf16* hid = (bf16*)(ws + 54525952);         // 32768 x 512 (32 MB) [dead after gemm2]
    bf16* pooled_bf = hid;                      // 16 MB, reuse after gemm2
    bf16* h2  = (bf16*)(ws + 71303168);         // 16 MB, upper half of hid

    float* out_obj = (float*)d_out;             // 64*256*512 f32 (33.5 MB)
    float* out_p   = (float*)d_out + 8388608;   // 64*512*512 f32
    bf16* new_o    = (bf16*)d_out;              // 32 MB scratch in out_obj region;
                                                // overwritten by gemm4 at the end

    cvt2_k<<<24576, 256, 0, stream>>>((const float4*)obj_f, (const float4*)pred_f,
                                      (bf16x4*)obj_bf, (bf16x4*)pred_bf);
    transpose4_k<<<2048, dim3(32, 8), 0, stream>>>(w1, w1t, w2, w2t, w3, w3t, w4, w4t);

    gemm_k<0, 4><<<1024, 256, 0, stream>>>(
        nullptr, w1t, b1, hid, nullptr, nullptr, edges, obj_bf, pred_bf, 1536);

    csr_k<<<64, 256, 0, stream>>>(edges, counts, starts, entries);

    gemm_k<1, 12><<<3072, 256, 0, stream>>>(
        hid, w2t, b2, new_s, out_p, new_o, nullptr, nullptr, nullptr, 512);

    pool_k<<<16384, 256, 0, stream>>>(entries, starts, counts, new_s, new_o, pooled_bf);

    gemm_k<2, 4><<<512, 256, 0, stream>>>(
        pooled_bf, w3t, b3, h2, nullptr, nullptr, nullptr, nullptr, nullptr, 512);
    gemm_k<3, 4><<<512, 256, 0, stream>>>(
        h2, w4t, b4, nullptr, out_obj, nullptr, nullptr, nullptr, nullptr, 512);
}